// Round 11
// baseline (425.597 us; speedup 1.0000x reference)
//
#include <hip/hip_runtime.h>
#include <hip/hip_bf16.h>
#include <cstdint>

#define D_MODEL 384
#define NHEAD 6
#define DHEAD 64
#define NPTS 2048
#define BATCH 8

typedef __attribute__((ext_vector_type(8))) short short8;
typedef __attribute__((ext_vector_type(4))) short short4v;
typedef __attribute__((ext_vector_type(4))) float floatx4;
typedef __attribute__((ext_vector_type(2))) unsigned int u32x2;

__device__ __forceinline__ float bf2f(unsigned short u) {
    return __uint_as_float(((unsigned int)u) << 16);
}

// round-to-nearest-even f32 -> bf16 (finite inputs only)
__device__ __forceinline__ unsigned short f2bf(float f) {
    unsigned int u = __float_as_uint(f);
    unsigned int r = (u + 0x7FFFu + ((u >> 16) & 1u)) >> 16;
    return (unsigned short)r;
}

// v_cvt_pk_bf16_f32: pack two f32 -> {bf16(lo), bf16(hi)} in one u32 (RNE)
__device__ __forceinline__ unsigned cvtpk(float lo, float hi) {
    unsigned r;
    asm("v_cvt_pk_bf16_f32 %0, %1, %2" : "=v"(r) : "v"(lo), "v"(hi));
    return r;
}

// 16x16x16 bf16 MFMA (A,B = 4 bf16/lane). Builtin if present, else exact
// gfx950 mnemonic per cdna4_isa.md §10.
__device__ __forceinline__ floatx4 mfma16(short4v a, short4v b, floatx4 c) {
#if __has_builtin(__builtin_amdgcn_mfma_f32_16x16x16bf16_1k)
    return __builtin_amdgcn_mfma_f32_16x16x16bf16_1k(a, b, c, 0, 0, 0);
#else
    floatx4 d;
    asm("v_mfma_f32_16x16x16_bf16 %0, %1, %2, %3" : "=v"(d) : "v"(a), "v"(b), "v"(c));
    return d;
#endif
}

__device__ __forceinline__ float gelu_tanh(float x) {
    float x3 = x * x * x;
    return 0.5f * x * (1.0f + tanhf(0.7978845608028654f * (x + 0.044715f * x3)));
}

// async 16B global -> LDS (wave-uniform LDS base + lane*16)
__device__ __forceinline__ void gload_lds16(const unsigned short* g, unsigned short* l) {
    __builtin_amdgcn_global_load_lds(
        (const __attribute__((address_space(1))) unsigned int*)g,
        (__attribute__((address_space(3))) unsigned int*)l, 16, 0, 0);
}

// Weight prep: fp32 [K,N] -> bf16 [N,K] (transposed), all 8 weights in one dispatch.
__global__ __launch_bounds__(256) void k_wprep(
    const float* __restrict__ wqkv, const float* __restrict__ wao,
    const float* __restrict__ wq, const float* __restrict__ wk,
    const float* __restrict__ wv, const float* __restrict__ wm,
    const float* __restrict__ w1, const float* __restrict__ w2,
    unsigned short* __restrict__ qkvT, unsigned short* __restrict__ aoT,
    unsigned short* __restrict__ gaT, unsigned short* __restrict__ mT,
    unsigned short* __restrict__ f1T, unsigned short* __restrict__ f2T) {
    __shared__ float tile[32][33];
    int id = blockIdx.x;
    const float* src;
    unsigned short* dst;
    int K, N;
    if (id < 432)       {            src = wqkv; dst = qkvT;            K = 384; N = 1152; }
    else if (id < 576)  { id -= 432; src = wao;  dst = aoT;             K = 384; N = 384; }
    else if (id < 720)  { id -= 576; src = wq;   dst = gaT;             K = 384; N = 384; }
    else if (id < 864)  { id -= 720; src = wk;   dst = gaT + 384 * 384; K = 384; N = 384; }
    else if (id < 1008) { id -= 864; src = wv;   dst = gaT + 768 * 384; K = 384; N = 384; }
    else if (id < 1296) { id -= 1008; src = wm;  dst = mT;              K = 768; N = 384; }
    else if (id < 1584) { id -= 1296; src = w1;  dst = f1T;             K = 384; N = 768; }
    else                { id -= 1584; src = w2;  dst = f2T;             K = 768; N = 384; }
    int ntiles = N >> 5;
    int nt = id % ntiles, kt = id / ntiles;
    int tx = threadIdx.x, ty = threadIdx.y;
#pragma unroll
    for (int i = 0; i < 32; i += 8)
        tile[ty + i][tx] = src[(size_t)(kt * 32 + ty + i) * N + nt * 32 + tx];
    __syncthreads();
#pragma unroll
    for (int i = 0; i < 32; i += 8)
        dst[(size_t)(nt * 32 + ty + i) * K + kt * 32 + tx] = f2bf(tile[tx][ty + i]);
}

// features fp32 [B, D, N] -> F bf16 [B, N, D]
__global__ __launch_bounds__(256) void k_transpose_in(const float* __restrict__ feat,
                                                      unsigned short* __restrict__ f) {
    __shared__ float tile[32][33];
    int b = blockIdx.z;
    int n0 = blockIdx.x * 32, d0 = blockIdx.y * 32;
    int tx = threadIdx.x, ty = threadIdx.y;
#pragma unroll
    for (int i = 0; i < 32; i += 8)
        tile[ty + i][tx] = feat[((size_t)b * D_MODEL + d0 + ty + i) * NPTS + n0 + tx];
    __syncthreads();
#pragma unroll
    for (int i = 0; i < 32; i += 8)
        f[((size_t)b * NPTS + n0 + ty + i) * D_MODEL + d0 + tx] = f2bf(tile[tx][ty + i]);
}

// FFIN bf16 [B, N, D] -> out fp32 [B, D, N]
__global__ __launch_bounds__(256) void k_transpose_out(const unsigned short* __restrict__ f,
                                                       float* __restrict__ out) {
    __shared__ float tile[32][33];
    int b = blockIdx.z;
    int d0 = blockIdx.x * 32, n0 = blockIdx.y * 32;
    int tx = threadIdx.x, ty = threadIdx.y;
#pragma unroll
    for (int i = 0; i < 32; i += 8)
        tile[ty + i][tx] = bf2f(f[((size_t)b * NPTS + n0 + ty + i) * D_MODEL + d0 + tx]);
    __syncthreads();
#pragma unroll
    for (int i = 0; i < 32; i += 8)
        out[((size_t)b * D_MODEL + d0 + ty + i) * NPTS + n0 + tx] = tile[tx][ty + i];
}

// V slice of QKV [M,1152] (cols 768..1152) -> VT [B,H,64,NPTS]
__global__ __launch_bounds__(256) void k_vt(const unsigned short* __restrict__ qkv,
                                            unsigned short* __restrict__ vt) {
    __shared__ unsigned short tile[32][33];
    int b = blockIdx.z;
    int h = blockIdx.y >> 1, d0 = (blockIdx.y & 1) * 32;
    int n0 = blockIdx.x * 32;
    int tx = threadIdx.x, ty = threadIdx.y;
#pragma unroll
    for (int i = 0; i < 32; i += 8)
        tile[ty + i][tx] =
            qkv[((size_t)b * NPTS + n0 + ty + i) * 1152 + 768 + h * 64 + d0 + tx];
    __syncthreads();
#pragma unroll
    for (int i = 0; i < 32; i += 8)
        vt[(((size_t)(b * NHEAD + h) * 64) + d0 + ty + i) * NPTS + n0 + tx] = tile[tx][ty + i];
}

// LayerNorm over D=384 (bf16 in/out, fp32 g/b), one block (128 thr) per row
__global__ __launch_bounds__(128) void k_layernorm(const unsigned short* __restrict__ x,
                                                   const float* __restrict__ g,
                                                   const float* __restrict__ bt,
                                                   unsigned short* __restrict__ y) {
    int row = blockIdx.x, t = threadIdx.x;
    const unsigned short* xr = x + (size_t)row * D_MODEL;
    float v0 = bf2f(xr[t]), v1 = bf2f(xr[t + 128]), v2 = bf2f(xr[t + 256]);
    float s = v0 + v1 + v2;
    float s2 = v0 * v0 + v1 * v1 + v2 * v2;
#pragma unroll
    for (int off = 32; off > 0; off >>= 1) {
        s += __shfl_xor(s, off, 64);
        s2 += __shfl_xor(s2, off, 64);
    }
    __shared__ float ps[2], ps2[2];
    if ((t & 63) == 0) { ps[t >> 6] = s; ps2[t >> 6] = s2; }
    __syncthreads();
    s = ps[0] + ps[1];
    s2 = ps2[0] + ps2[1];
    float mean = s * (1.0f / 384.0f);
    float var = s2 * (1.0f / 384.0f) - mean * mean;
    var = fmaxf(var, 0.0f);
    float inv = 1.0f / sqrtf(var + 1e-5f);
    unsigned short* yr = y + (size_t)row * D_MODEL;
    yr[t]       = f2bf((v0 - mean) * inv * g[t]       + bt[t]);
    yr[t + 128] = f2bf((v1 - mean) * inv * g[t + 128] + bt[t + 128]);
    yr[t + 256] = f2bf((v2 - mean) * inv * g[t + 256] + bt[t + 256]);
}

// KNN v3: one wave per query, exact two-pass u32 selection.
__global__ __launch_bounds__(256) void k_knn(const float* __restrict__ coords,
                                             int* __restrict__ idx) {
    __shared__ float4 cpts[NPTS];
    int b = blockIdx.x >> 9;             // 512 blocks per batch
    int q0 = (blockIdx.x & 511) * 4;     // 4 queries (waves) per block
    const float* cb = coords + (size_t)b * 3 * NPTS;
    int tid = threadIdx.x;
#pragma unroll
    for (int i = 0; i < 8; i++) {
        int m = tid + i * 256;
        float x = cb[m], y = cb[NPTS + m], z = cb[2 * NPTS + m];
        float sq = __fadd_rn(__fadd_rn(__fmul_rn(x, x), __fmul_rn(y, y)), __fmul_rn(z, z));
        cpts[m] = make_float4(x, y, z, sq);
    }
    __syncthreads();
    int wv = tid >> 6, lane = tid & 63;
    int n = q0 + wv;
    float4 qp = cpts[n];
    float qx = qp.x, qy = qp.y, qz = qp.z, sqn = qp.w;
    unsigned keys[32];
    unsigned h[8];
#pragma unroll
    for (int k = 0; k < 8; k++) h[k] = 0xFFFFFFFFu;
#pragma unroll
    for (int j = 0; j < 32; j++) {
        float4 cp = cpts[j * 64 + lane];
        float dot = __fadd_rn(__fadd_rn(__fmul_rn(qx, cp.x), __fmul_rn(qy, cp.y)),
                              __fmul_rn(qz, cp.z));
        float d2 = __fsub_rn(__fadd_rn(sqn, cp.w), __fmul_rn(2.0f, dot));
        unsigned u = __float_as_uint(d2);
        u ^= (unsigned)(((int)u >> 31)) | 0x80000000u;  // order-preserving map
        keys[j] = u;
        unsigned cur = u;  // unconditional sorted-insert (no-op if u >= h[7])
#pragma unroll
        for (int t2 = 0; t2 < 8; t2++) {
            unsigned lo = h[t2] < cur ? h[t2] : cur;
            cur = h[t2] < cur ? cur : h[t2];
            h[t2] = lo;
        }
    }
    // Merge: serial-extract 8 smallest values of the union -> T8
    unsigned curh = h[0];
    unsigned T8 = 0;
#pragma unroll
    for (int r = 0; r < 8; r++) {
        unsigned w = curh;
#pragma unroll
        for (int off = 1; off < 64; off <<= 1) {
            unsigned o = __shfl_xor(w, off, 64);
            w = o < w ? o : w;
        }
        T8 = w;
        if (r < 7) {
            unsigned long long mask = __ballot(curh == w);
            if (curh == w && (mask & ((1ull << lane) - 1ull)) == 0) {
#pragma unroll
                for (int t2 = 0; t2 < 7; t2++) h[t2] = h[t2 + 1];
                h[7] = 0xFFFFFFFFu;
                curh = h[0];
            }
        }
    }
    // Pass 2: emit strict winners; track min eq index
    int* outr = idx + ((size_t)b * NPTS + n) * 8;
    int cnt = 0;
    unsigned meq = 0xFFFFFFFFu;
#pragma unroll
    for (int j = 0; j < 32; j++) {
        unsigned m = (unsigned)(j * 64 + lane);
        bool strict = keys[j] < T8;
        unsigned long long msk = __ballot(strict);
        if (strict) {
            int pos = cnt + (int)__popcll(msk & ((1ull << lane) - 1ull));
            outr[pos] = (int)m;
        }
        cnt += (int)__popcll(msk);
        if (keys[j] == T8 && m < meq) meq = m;
    }
    // Fill remaining slots with lowest-index key==T8 candidates
    while (cnt < 8) {
        unsigned w = meq;
#pragma unroll
        for (int off = 1; off < 64; off <<= 1) {
            unsigned o = __shfl_xor(w, off, 64);
            w = o < w ? o : w;
        }
        bool winner = (meq == w);
        if (winner) outr[cnt] = (int)w;
        cnt++;
        if (cnt >= 8) break;
        if (winner) {  // rare: advance to next eq index > w
            meq = 0xFFFFFFFFu;
#pragma unroll
            for (int j = 0; j < 32; j++) {
                unsigned m = (unsigned)(j * 64 + lane);
                if (keys[j] == T8 && m > w && m < meq) meq = m;
            }
        }
    }
}

// MFMA GEMM v9: 128x128 tile, BK=32, 3-slot LDS ring + COUNTED vmcnt barriers
// (T3/T4 minimum form). Body t: stage(t+2) -> compute(t) -> s_waitcnt vmcnt(4)
// (keeps the 4 just-issued stage(t+2) loads in flight; in-order vmcnt
// completion => stage(t+1) fully landed) -> raw s_barrier + sched_barrier(0).
// Never vmcnt(0) in the main loop (the __syncthreads full-drain was the v8
// stall: 16 MFMAs can't hide a 300-600cy DMA). WAR safe: stage(t+3) (issued
// iter t+1, post-barrier) overwrites slot t%3 whose ds_reads completed before
// iter-t's barrier (compiler wait-before-use). Same math/layout as v8.
__global__ __launch_bounds__(256) void k_gemm(const unsigned short* __restrict__ A, int lda,
                                              const unsigned short* __restrict__ WT,
                                              const float* __restrict__ bias,
                                              const unsigned short* __restrict__ res,
                                              unsigned short* __restrict__ C, int ldc,
                                              int K, int act, int NX) {
    __shared__ unsigned short Alds[3][128 * 32];  // 3 x 8 KB ring: [slot][row][32]
    __shared__ unsigned short Wlds[3][128 * 32];  // 3 x 8 KB ring: [slot][nrow][32]
    int tid = threadIdx.x;
    int wv = tid >> 6, lane = tid & 63;
    int l15 = lane & 15, quad = lane >> 4;
    // XCD-aware block decode: id%8 = XCD (HW round-robin). 16 y-panels per XCD.
    int id = blockIdx.x;
    int xcd = id & 7, slot = id >> 3;
    int y = xcd * 16 + slot / NX;
    int x = slot % NX;
    int row0 = y * 128, col0 = x * 128;
    int wm = wv >> 1, wn = wv & 1;
    int wbase = tid & 192;  // wv*64
    floatx4 acc[4][4];
#pragma unroll
    for (int i = 0; i < 4; i++)
#pragma unroll
        for (int j = 0; j < 4; j++) acc[i][j] = (floatx4){0.f, 0.f, 0.f, 0.f};
    // stage one BK=32 chunk of A and W into ring slot sl (4 gloads per thread).
    auto stage = [&](int sl, int k0) {
#pragma unroll
        for (int i = 0; i < 2; i++) {
            int sid = i * 256 + tid;
            int row = sid >> 2, ko = sid & 3;
            gload_lds16(A + (size_t)(row0 + row) * lda + k0 + ko * 8,
                        &Alds[sl][(size_t)(i * 256 + wbase) * 8]);
            gload_lds16(WT + (size_t)(col0 + row) * K + k0 + ko * 8,
                        &Wlds[sl][(size_t)(i * 256 + wbase) * 8]);
        }
    };
    int nst = K >> 5;
    stage(0, 0);
    stage(1, 32);
    asm volatile("s_waitcnt vmcnt(4)" ::: "memory");  // slot 0 landed; slot 1 in flight
    __builtin_amdgcn_s_barrier();
    __builtin_amdgcn_sched_barrier(0);
    for (int t = 0; t < nst; ++t) {
        int sl = t % 3;
        if (t + 2 < nst) stage((t + 2) % 3, (t + 2) * 32);  // DMA 2 steps ahead
        short8 af[4], bf[4];
#pragma unroll
        for (int i = 0; i < 4; i++)
            af[i] = *(const short8*)&Alds[sl][(wm * 64 + i * 16 + l15) * 32 + quad * 8];
#pragma unroll
        for (int j = 0; j < 4; j++)
            bf[j] = *(const short8*)&Wlds[sl][(wn * 64 + j * 16 + l15) * 32 + quad * 8];
#pragma unroll
        for (int i = 0; i < 4; i++)
#pragma unroll
            for (int j = 0; j < 4; j++)
                acc[i][j] =
                    __builtin_amdgcn_mfma_f32_16x16x32_bf16(bf[j], af[i], acc[i][j], 0, 0, 0);
        if (t + 1 < nst) {
            if (t + 2 < nst)
                asm volatile("s_waitcnt vmcnt(4)" ::: "memory");  // (t+1) landed, (t+2) flying
            else
                asm volatile("s_waitcnt vmcnt(0)" ::: "memory");  // tail: drain last stage
            __builtin_amdgcn_s_barrier();
            __builtin_amdgcn_sched_barrier(0);
        }
    }
    // acc[i][j] is C^T-layout: D rows = n (quad*4+reg within j-tile), cols = m (l15)
#pragma unroll
    for (int i = 0; i < 4; i++) {
        int r = row0 + wm * 64 + i * 16 + l15;
#pragma unroll
        for (int j = 0; j < 4; j++) {
            int cb = col0 + wn * 64 + j * 16 + quad * 4;
            float4 bv = bias ? *(const float4*)(bias + cb) : make_float4(0.f, 0.f, 0.f, 0.f);
            float v0 = acc[i][j][0] + bv.x;
            float v1 = acc[i][j][1] + bv.y;
            float v2 = acc[i][j][2] + bv.z;
            float v3 = acc[i][j][3] + bv.w;
            if (act == 1) {
                v0 = gelu_tanh(v0); v1 = gelu_tanh(v1);
                v2 = gelu_tanh(v2); v3 = gelu_tanh(v3);
            }
            if (res) {
                uint2 rv = *(const uint2*)(res + (size_t)r * ldc + cb);
                const unsigned short* rs = (const unsigned short*)&rv;
                v0 += bf2f(rs[0]); v1 += bf2f(rs[1]);
                v2 += bf2f(rs[2]); v3 += bf2f(rs[3]);
            }
            ushort4 u;
            u.x = f2bf(v0); u.y = f2bf(v1); u.z = f2bf(v2); u.w = f2bf(v3);
            *(ushort4*)(C + (size_t)r * ldc + cb) = u;
        }
    }
}

// MFMA flash attention v10 = v7 + P-only software pipeline (hazard-free):
// cross-iteration state is ONLY the P fragments (pure VALU register outputs,
// no memory hazard). V is read in the CONSUMING iteration (wait-before-use
// precedes that iteration's barrier) from a 4-slot V ring: V(t) written in
// iter t-1, read in iter t+1, overwritten in iter t+3 (2 barriers of slack).
// K double-buffered, read in its own iteration (as v7). Body = QK(t)+softmax
// (serial chain) alongside PV(t-1) (independent loads+MFMAs) -> scheduler
// overlaps matrix and VALU pipes. t=0 does QK only; drain does PV(31).
// Accumulation order identical to v7 -> bit-identical numerics.
__global__ __launch_bounds__(256, 3) void k_attn(const unsigned short* __restrict__ qkv,
                                                 const unsigned short* __restrict__ vt,
                                                 unsigned short* __restrict__ attn) {
    __shared__ unsigned short Klds[2][64 * 64];  // 16 KB: [buf][key][dim] (swizzled slots)
    __shared__ unsigned short VTl[4][64 * 64];   // 32 KB: [slot][dim][key] (swizzled slots)
    // XCD decode: id%8 = XCD; 96 slots/XCD = 6 pairs x 16 tiles
    int id = blockIdx.x;
    int xcd = id & 7, slot = id >> 3;
    int pair = xcd * 6 + (slot >> 4);    // 48 pairs total, 6 per XCD
    int tile = slot & 15;
    int b = pair / 6, h = pair % 6;
    int tid = threadIdx.x;
    int wv = tid >> 6, lane = tid & 63;
    int l15 = lane & 15, quad = lane >> 4;
    int qbase = tile * 128 + wv * 32;
    const unsigned short* qkvb = qkv + (size_t)b * NPTS * 1152;
    const unsigned short* vtb = vt + (size_t)(b * NHEAD + h) * 64 * NPTS;
    const float SC = 0.18033688011112042f;  // 0.125 * log2(e)
    short8 qf[2][2];
#pragma unroll
    for (int qt = 0; qt < 2; qt++) {
        const unsigned short* qptr =
            qkvb + (size_t)(qbase + qt * 16 + l15) * 1152 + h * 64 + quad * 8;
        qf[qt][0] = *(const short8*)qptr;
        qf[qt][1] = *(const short8*)(qptr + 32);
#pragma unroll
        for (int g = 0; g < 2; g++) {  // fold softmax scale into Q once
            short8 v = qf[qt][g];
#pragma unroll
            for (int e = 0; e < 8; e++)
                v[e] = (short)f2bf(bf2f((unsigned short)v[e]) * SC);
            qf[qt][g] = v;
        }
    }
    short4v ones4;
#pragma unroll
    for (int e = 0; e < 4; e++) ones4[e] = (short)0x3F80;  // bf16 1.0
    int x7 = l15 & 7;
    int sk0 = ((quad ^ x7) << 4);        // K read: swizzled slot, dims 0..31
    int sk1 = (((quad + 4) ^ x7) << 4);  // K read: swizzled slot, dims 32..63
    int vslot[4];                        // V read: per-kt swizzled slot
#pragma unroll
    for (int kt = 0; kt < 4; kt++) vslot[kt] = (((kt * 2 + (quad >> 1)) ^ x7) << 4);
    int vsub = (quad & 1) * 8;           // 8B half within the 16B slot
    int sdg = tid & 7;                   // staging: 16B slot within row
    floatx4 o[2][4];
#pragma unroll
    for (int qt = 0; qt < 2; qt++)
#pragma unroll
        for (int ct = 0; ct < 4; ct++) o[qt][ct] = (floatx4){0.f, 0.f, 0.f, 0.f};
    floatx4 l4[2];
    l4[0] = (floatx4){0.f, 0.f, 0.f, 0.f};
    l4[1] = (floatx4){0.f, 0.f, 0.f, 0.f};

    // stage tile t: K -> Klds[t&1], V -> VTl[t&3]
    auto stage = [&](int t) {
        int k0 = t * 64;
#pragma unroll
        for (int i = 0; i < 2; i++) {
            int sid = i * 256 + tid;
            int row = sid >> 3;
            int sl = sdg ^ (row & 7);  // inverse-swizzled global slot
            gload_lds16(qkvb + (size_t)(k0 + row) * 1152 + 384 + h * 64 + sl * 8,
                        &Klds[t & 1][(size_t)(i * 256 + (tid & 192)) * 8]);
            gload_lds16(vtb + (size_t)row * NPTS + k0 + sl * 8,
                        &VTl[t & 3][(size_t)(i * 256 + (tid & 192)) * 8]);
        }
    };
    // QK^T(t) + softmax -> pfc (swapped operands: lane holds P[key][q=l15])
    auto qkchain = [&](int t, short4v (&pfc)[2][4]) {
        const char* Kb = (const char*)&Klds[t & 1][0];
        short8 kf[4][2];
#pragma unroll
        for (int ct = 0; ct < 4; ct++) {
            kf[ct][0] = *(const short8*)(Kb + (ct * 16 + l15) * 128 + sk0);
            kf[ct][1] = *(const short8*)(Kb + (ct * 16 + l15) * 128 + sk1);
        }
#pragma unroll
        for (int qt = 0; qt < 2; qt++) {
#pragma unroll
            for (int ct = 0; ct < 4; ct++) {
                floatx4 z = (floatx4){0.f, 0.f, 0.f, 0.f};
                z = __builtin_amdgcn_mfma_f32_16x16x32_bf16(kf[ct][0], qf[qt][0], z, 0, 0, 0);
                z = __builtin_amdgcn_mfma_f32_16x16x32_bf16(kf[ct][1], qf[qt][1], z, 0, 0, 0);
                float p0 = __builtin_amdgcn_exp2f(z[0]);
                float p1 = __builtin_amdgcn_exp2f(z[1]);
                float p2 = __builtin_amdgcn_exp2f(z[2]);
                float p3 = __builtin_amdgcn_exp2f(z[3]);
                u32x2 pk;
                pk.x = cvtpk(p0, p1);
                pk.y = cvtpk(p2, p3);
                pfc[qt][ct] = __builtin_bit_cast(short4v, pk);  // B-frag of mfma16
            }
        }
    };
    // PV(t): V read fresh from VTl[t&3] (consumed by MFMA in this iteration)
    auto pv = [&](int t, short4v (&pfp)[2][4]) {
        const char* Vb = (const char*)&VTl[t & 3][0] + l15 * 128 + vsub;
#pragma unroll
        for (int ctd = 0; ctd < 4; ctd++) {
            short4v va[4];
#pragma unroll
            for (int kt = 0; kt < 4; kt++)
                va[kt] = *(const short4v*)(Vb + ctd * 2048 + vslot[kt]);
#pragma unroll
            for (int kt = 0; kt < 4; kt++)
#pragma unroll
                for (int qt = 0; qt < 2; qt++)
                    o[qt][ctd] = mfma16(va[kt], pfp[qt][kt], o[qt][ctd]);
        }
#pragma unroll
        for (int qt = 0; qt < 2; qt++)
#pragma unroll
            for (int kt = 0; kt < 4; kt++) l4[qt] = mfma16(ones4, pfp[qt][kt], l4[qt]);
    };

    short4v pfA[2][4], pfB[2][4];
    stage(0);
    __syncthreads();
    stage(1);
    qkchain(0, pfA);  // no PV at t=0
    __syncthreads();
    for (int tt = 0; tt < 15; ++tt) {
        int t1 = 2 * tt + 1, t2 = 2 * tt + 2;
        stage(t1 + 1);           // tiles 2..30
        qkchain(t1, pfB);
        pv(t1 - 1, pfA);
        __syncthreads();
        stage(t2 + 1);           // tiles 3..31
        qkchain(t2, pfA);
        pv(t2 - 1, pfB);
        __syncthreads();
    }
    qkchain(31, pfB);
    pv(30, pfA);
    pv(31, pfB);  // V(31) staged at tt=14, drained by that body's barrier

#pragma unroll
    for (int qt = 0; qt < 2; qt++) {
        float linv = 1.0f / l4[qt][0];
#pragma unroll
        for (int ct = 0; ct < 4; ct++) {
            ushort4 u;
            u.x = f2bf(o[qt][ct][0] * linv);
            u.y = f2bf(o[qt][ct][1] * linv);
            u.z = f2bf(o[qt][ct][2] * linv);
            u.w = f2bf(o[qt][ct][3] * linv);
            *(ushort4*)(attn + ((size_t)b * NPTS + qbase + qt * 16 + l15) * 384 + h * 64 +
                        ct * 16 + quad * 4) = u;
        }
    }
}

// Graph attention: gq/nk/nv are column-slices of GAP [M,1152]. One wave per point.
// Writes geom into CAT[:, 384:768] (row stride 768).
__global__ __launch_bounds__(64) void k_geom(const unsigned short* __restrict__ gap,
                                             const int* __restrict__ idx,
                                             unsigned short* __restrict__ cat) {
    int r = blockIdx.x;
    int b = r >> 11;
    int t = threadIdx.x;
    int nb[8];
#pragma unroll
    for (int k = 0; k < 8; k++) nb[k] = idx[(size_t)r * 8 + k];
    const unsigned short* gqr = gap + (size_t)r * 1152;
    float qv[6];
#pragma unroll
    for (int j = 0; j < 6; j++) qv[j] = bf2f(gqr[t + 64 * j]);
    float s[8];
#pragma unroll
    for (int k = 0; k < 8; k++) {
        const unsigned short* nkr = gap + ((size_t)b * NPTS + nb[k]) * 1152 + 384;
        float acc = 0.0f;
#pragma unroll
        for (int j = 0; j < 6; j++) acc += qv[j] * bf2f(nkr[t + 64 * j]);
#pragma unroll
        for (int mm = 32; mm > 0; mm >>= 1) acc += __shfl_xor(acc, mm, 64);
        s[k] = acc * 0.05103103630798287f;  // 1/sqrt(384)
    }
    float mx = s[0];
#pragma unroll
    for (int k = 1; k < 8; k++) mx = fmaxf(mx, s[k]);
    float w[8];
    float sum = 0.0f;
#pragma unroll
    for (int k = 0; k < 8; k++) { w[k] = __expf(s[k] - mx); sum += w[k]; }
    float inv = 1.0f / sum;
    unsigned short* outr = cat + (size_t)r * 768 + 384;
#pragma unroll
    for (int j = 0; j < 6; j++) {
        int d = t + 64 * j;
        float acc = 0.0f;
#pragma unroll
        for (int k = 0; k < 8; k++)
            acc += w[k] * bf2f(gap[((size_t)b * NPTS + nb[k]) * 1152 + 768 + d]);
        outr[d] = f2bf(acc * inv);
    }
}

extern "C" void kernel_launch(void* const* d_in, const int* in_sizes, int n_in,
                              void* d_out, int out_size, void* d_ws, size_t ws_size,
                              hipStream_t stream) {
    (void)in_sizes; (void)n_in; (void)out_size; (void)ws_size;
    const float* coords     = (const float*)d_in[0];
    const float* features   = (const float*)d_in[1];
    const float* ln1_g      = (const float*)d_in[2];
    const float* ln1_b      = (const float*)d_in[3];
    const float* w_qkv      = (const float*)d_in[4];
    const float* w_attn_out = (const float*)d_in[5];
    const float* b_attn_out = (const float*)d_in[6];
    const float* ga_wq      = (const float*)d_in[7];
    const float* ga_wk      = (const float*)d_in[8];
    const float* ga_wv      = (const float*)d_in[9];
    const float* merge_w    = (const float*)d_in[10];
    const float* merge_b    = (const float*)d_in[11];
    const float* ln2_g      = (const float*)d_in[12];
    const float* ln2_b      = (const float*)d_in[13];
    const float* ff_w1      = (const float*)d_in[14];
    const float* ff_b1      = (const float*)d_in[15];
    const float* ff_w2      = (const float*)d_in[16];
    const float* ff_b2      = (const float*)d_in[17];

    // Workspace (bf16 units of SZ = 6,291,456 elems = 12 MiB). Overlay schedule:
    //   u0 F | u1 NF->HB | u2-4 QKV -> (CAT=u2-3, GAP=u4-6 after attn/AO) |
    //   u5 ATTN | u6 VT (dead before GAP gemm) | F2=u4 after geom | T1=u5-6 |
    //   FFIN=u2 | IDX + transposed weights after u7 (~4.3 MB). Peak ~100 MiB.
    unsigned short* W0 = (unsigned short*)d_ws;
    const size_t SZ = (size_t)BATCH * NPTS * D_MODEL;  // 6291456
    unsigned short* F    = W0 + 0 * SZ;
    unsigned short* NF   = W0 + 1 * SZ;
    unsigned short* QKV  = W0 + 2 * SZ;   // 3 units
    unsigned short* ATTN = W0 + 5 * SZ;
    unsigned short* VT   = W0 + 6 * SZ;   // [B,H,64,NPTS] = 1 unit
    unsigned short* CAT  = W0 + 2 * SZ;   // 2 units [M,768]
    unsigned short* GAP  = W0 + 4 * SZ;   // 3 units [M,1152]
    unsigned short* F2   = W0 + 4 * SZ;   // after GAP dead
    unsigned short* HB   = W0 + 1 * SZ;
    unsigned short* T1   = W0 + 5 * SZ;   // 2 units [M,768]
    unsigned short* FFIN = W0 + 2 * SZ;
    int*            IDX  = (int*)(W0 + 7 * SZ);
    unsigned short* WTS  = W0 + 7 * SZ + 262144;  // after IDX (512 KB)
    unsigned short* qkvT = WTS;                     // [1152,384]
    unsigned short* aoT  = qkvT + 442368;           // [384,384]
    unsigned short* gaT  = aoT + 147456;            // [1152,384]
    unsigned short* mT   = gaT + 442368;            // [384,768]
    unsigned short* f1T  = mT + 294912;             // [768,384]
    unsigned short* f2T  = f1T + 294912;            // [384,768]

    const int M = BATCH * NPTS;  // 16384

    k_wprep<<<1872, dim3(32, 8), 0, stream>>>(w_qkv, w_attn_out, ga_wq, ga_wk, ga_wv,
                                              merge_w, ff_w1, ff_w2,
                                              qkvT, aoT, gaT, mT, f1T, f2T);
    k_transpose_in<<<dim3(NPTS / 32, D_MODEL / 32, BATCH), dim3(32, 8), 0, stream>>>(features, F);
    k_layernorm<<<M, 128, 0, stream>>>(F, ln1_g, ln1_b, NF);
    k_knn<<<BATCH * (NPTS / 4), 256, 0, stream>>>(coords, IDX);
    // QKV = NF @ w_qkv
    k_gemm<<<9 * 128, 256, 0, stream>>>(NF, 384, qkvT, nullptr, nullptr,
                                        QKV, 1152, 384, 0, 9);
    k_vt<<<dim3(NPTS / 32, 2 * NHEAD, BATCH), dim3(32, 8), 0, stream>>>(QKV, VT);
    k_attn<<<768, 256, 0, stream>>>(QKV, VT, ATTN);
    // CAT[:, :384] = ATTN @ w_attn_out + b_attn_out
    k_gemm<<<3 * 128, 256, 0, stream>>>(ATTN, 384, aoT, b_attn_out, nullptr,
                                        CAT, 768, 384, 0, 3);
    // GAP = NF @ [ga_wq | ga_wk | ga_wv]
    k_gemm<<<9 * 128, 256, 0, stream>>>(NF, 384, gaT, nullptr, nullptr,
                                        GAP, 1152, 384, 0, 9);
    k_geom<<<M, 64, 0, stream>>>(GAP, IDX, CAT);
    // F2 = CAT @ merge_w + merge_b + F
    k_gemm<<<3 * 128, 256, 0, stream>>>(CAT, 768, mT, merge_b, F,
                                        F2, 384, 768, 0, 3);
    k_layernorm<<<M, 128, 0, stream>>>(F2, ln2_g, ln2_b, HB);
    // T1 = gelu(HB @ ff_w1 + ff_b1)
    k_gemm<<<6 * 128, 256, 0, stream>>>(HB, 384, f1T, ff_b1, nullptr,
                                        T1, 768, 384, 1, 6);
    // FFIN = F2 + T1 @ ff_w2 + ff_b2
    k_gemm<<<3 * 128, 256, 0, stream>>>(T1, 768, f2T, ff_b2, F2,
                                        FFIN, 384, 768, 0, 3);
    k_transpose_out<<<dim3(D_MODEL / 32, NPTS / 32, BATCH), dim3(32, 8), 0, stream>>>(
        FFIN, (float*)d_out);
}

// Round 12
// 415.102 us; speedup vs baseline: 1.0253x; 1.0253x over previous
//
#include <hip/hip_runtime.h>
#include <hip/hip_bf16.h>
#include <cstdint>

#define D_MODEL 384
#define NHEAD 6
#define DHEAD 64
#define NPTS 2048
#define BATCH 8

typedef __attribute__((ext_vector_type(8))) short short8;
typedef __attribute__((ext_vector_type(4))) short short4v;
typedef __attribute__((ext_vector_type(4))) float floatx4;
typedef __attribute__((ext_vector_type(2))) unsigned int u32x2;

__device__ __forceinline__ float bf2f(unsigned short u) {
    return __uint_as_float(((unsigned int)u) << 16);
}

// round-to-nearest-even f32 -> bf16 (finite inputs only)
__device__ __forceinline__ unsigned short f2bf(float f) {
    unsigned int u = __float_as_uint(f);
    unsigned int r = (u + 0x7FFFu + ((u >> 16) & 1u)) >> 16;
    return (unsigned short)r;
}

// v_cvt_pk_bf16_f32: pack two f32 -> {bf16(lo), bf16(hi)} in one u32 (RNE)
__device__ __forceinline__ unsigned cvtpk(float lo, float hi) {
    unsigned r;
    asm("v_cvt_pk_bf16_f32 %0, %1, %2" : "=v"(r) : "v"(lo), "v"(hi));
    return r;
}

// 16x16x16 bf16 MFMA (A,B = 4 bf16/lane). Builtin if present, else exact
// gfx950 mnemonic per cdna4_isa.md §10.
__device__ __forceinline__ floatx4 mfma16(short4v a, short4v b, floatx4 c) {
#if __has_builtin(__builtin_amdgcn_mfma_f32_16x16x16bf16_1k)
    return __builtin_amdgcn_mfma_f32_16x16x16bf16_1k(a, b, c, 0, 0, 0);
#else
    floatx4 d;
    asm("v_mfma_f32_16x16x16_bf16 %0, %1, %2, %3" : "=v"(d) : "v"(a), "v"(b), "v"(c));
    return d;
#endif
}

__device__ __forceinline__ float gelu_tanh(float x) {
    float x3 = x * x * x;
    return 0.5f * x * (1.0f + tanhf(0.7978845608028654f * (x + 0.044715f * x3)));
}

// async 16B global -> LDS (wave-uniform LDS base + lane*16)
__device__ __forceinline__ void gload_lds16(const unsigned short* g, unsigned short* l) {
    __builtin_amdgcn_global_load_lds(
        (const __attribute__((address_space(1))) unsigned int*)g,
        (__attribute__((address_space(3))) unsigned int*)l, 16, 0, 0);
}

// Weight prep: fp32 [K,N] -> bf16 [N,K] (transposed), all 8 weights in one dispatch.
__global__ __launch_bounds__(256) void k_wprep(
    const float* __restrict__ wqkv, const float* __restrict__ wao,
    const float* __restrict__ wq, const float* __restrict__ wk,
    const float* __restrict__ wv, const float* __restrict__ wm,
    const float* __restrict__ w1, const float* __restrict__ w2,
    unsigned short* __restrict__ qkvT, unsigned short* __restrict__ aoT,
    unsigned short* __restrict__ gaT, unsigned short* __restrict__ mT,
    unsigned short* __restrict__ f1T, unsigned short* __restrict__ f2T) {
    __shared__ float tile[32][33];
    int id = blockIdx.x;
    const float* src;
    unsigned short* dst;
    int K, N;
    if (id < 432)       {            src = wqkv; dst = qkvT;            K = 384; N = 1152; }
    else if (id < 576)  { id -= 432; src = wao;  dst = aoT;             K = 384; N = 384; }
    else if (id < 720)  { id -= 576; src = wq;   dst = gaT;             K = 384; N = 384; }
    else if (id < 864)  { id -= 720; src = wk;   dst = gaT + 384 * 384; K = 384; N = 384; }
    else if (id < 1008) { id -= 864; src = wv;   dst = gaT + 768 * 384; K = 384; N = 384; }
    else if (id < 1296) { id -= 1008; src = wm;  dst = mT;              K = 768; N = 384; }
    else if (id < 1584) { id -= 1296; src = w1;  dst = f1T;             K = 384; N = 768; }
    else                { id -= 1584; src = w2;  dst = f2T;             K = 768; N = 384; }
    int ntiles = N >> 5;
    int nt = id % ntiles, kt = id / ntiles;
    int tx = threadIdx.x, ty = threadIdx.y;
#pragma unroll
    for (int i = 0; i < 32; i += 8)
        tile[ty + i][tx] = src[(size_t)(kt * 32 + ty + i) * N + nt * 32 + tx];
    __syncthreads();
#pragma unroll
    for (int i = 0; i < 32; i += 8)
        dst[(size_t)(nt * 32 + ty + i) * K + kt * 32 + tx] = f2bf(tile[tx][ty + i]);
}

// Fused transpose_in + LayerNorm1: reads fp32 [B,D,N] coalesced, LN over D=384
// computed FROM FP32 (closer to reference than bf16-input LN), writes both
// F (pre-LN bf16) and NF (post-LN bf16) as aligned short8.
// Block = 32 n-lanes x 8 d-groups (48 dims each); grid (NPTS/32, BATCH).
__global__ __launch_bounds__(256) void k_lnin(const float* __restrict__ feat,
                                              const float* __restrict__ g,
                                              const float* __restrict__ bt,
                                              unsigned short* __restrict__ F,
                                              unsigned short* __restrict__ NF) {
    int b = blockIdx.y;
    int n0 = blockIdx.x * 32;
    int tid = threadIdx.x;
    int tx = tid & 31;   // n offset
    int ty = tid >> 5;   // d-group (48 dims)
    const float* fb = feat + ((size_t)b * D_MODEL + ty * 48) * NPTS + n0 + tx;
    float val[48];
    float s = 0.f, s2 = 0.f;
#pragma unroll
    for (int j = 0; j < 48; j++) {
        float v = fb[(size_t)j * NPTS];
        val[j] = v;
        s += v;
        s2 += v * v;
    }
    __shared__ float ps[8][32], ps2[8][32];
    ps[ty][tx] = s;
    ps2[ty][tx] = s2;
    __syncthreads();
    s = 0.f;
    s2 = 0.f;
#pragma unroll
    for (int k = 0; k < 8; k++) { s += ps[k][tx]; s2 += ps2[k][tx]; }
    float mean = s * (1.0f / 384.0f);
    float var = fmaxf(s2 * (1.0f / 384.0f) - mean * mean, 0.0f);
    float inv = 1.0f / sqrtf(var + 1e-5f);
    size_t rbase = ((size_t)b * NPTS + n0 + tx) * D_MODEL + ty * 48;
#pragma unroll
    for (int c = 0; c < 6; c++) {
        short8 fv, nv;
#pragma unroll
        for (int e = 0; e < 8; e++) {
            int j = c * 8 + e;
            int d = ty * 48 + j;
            fv[e] = (short)f2bf(val[j]);
            nv[e] = (short)f2bf((val[j] - mean) * inv * g[d] + bt[d]);
        }
        *(short8*)(F + rbase + c * 8) = fv;
        *(short8*)(NF + rbase + c * 8) = nv;
    }
}

// LayerNorm over D=384 (bf16 in/out, fp32 g/b), one block (128 thr) per row
__global__ __launch_bounds__(128) void k_layernorm(const unsigned short* __restrict__ x,
                                                   const float* __restrict__ g,
                                                   const float* __restrict__ bt,
                                                   unsigned short* __restrict__ y) {
    int row = blockIdx.x, t = threadIdx.x;
    const unsigned short* xr = x + (size_t)row * D_MODEL;
    float v0 = bf2f(xr[t]), v1 = bf2f(xr[t + 128]), v2 = bf2f(xr[t + 256]);
    float s = v0 + v1 + v2;
    float s2 = v0 * v0 + v1 * v1 + v2 * v2;
#pragma unroll
    for (int off = 32; off > 0; off >>= 1) {
        s += __shfl_xor(s, off, 64);
        s2 += __shfl_xor(s2, off, 64);
    }
    __shared__ float ps[2], ps2[2];
    if ((t & 63) == 0) { ps[t >> 6] = s; ps2[t >> 6] = s2; }
    __syncthreads();
    s = ps[0] + ps[1];
    s2 = ps2[0] + ps2[1];
    float mean = s * (1.0f / 384.0f);
    float var = s2 * (1.0f / 384.0f) - mean * mean;
    var = fmaxf(var, 0.0f);
    float inv = 1.0f / sqrtf(var + 1e-5f);
    unsigned short* yr = y + (size_t)row * D_MODEL;
    yr[t]       = f2bf((v0 - mean) * inv * g[t]       + bt[t]);
    yr[t + 128] = f2bf((v1 - mean) * inv * g[t + 128] + bt[t + 128]);
    yr[t + 256] = f2bf((v2 - mean) * inv * g[t + 256] + bt[t + 256]);
}

// KNN v3: one wave per query, exact two-pass u32 selection.
__global__ __launch_bounds__(256) void k_knn(const float* __restrict__ coords,
                                             int* __restrict__ idx) {
    __shared__ float4 cpts[NPTS];
    int b = blockIdx.x >> 9;             // 512 blocks per batch
    int q0 = (blockIdx.x & 511) * 4;     // 4 queries (waves) per block
    const float* cb = coords + (size_t)b * 3 * NPTS;
    int tid = threadIdx.x;
#pragma unroll
    for (int i = 0; i < 8; i++) {
        int m = tid + i * 256;
        float x = cb[m], y = cb[NPTS + m], z = cb[2 * NPTS + m];
        float sq = __fadd_rn(__fadd_rn(__fmul_rn(x, x), __fmul_rn(y, y)), __fmul_rn(z, z));
        cpts[m] = make_float4(x, y, z, sq);
    }
    __syncthreads();
    int wv = tid >> 6, lane = tid & 63;
    int n = q0 + wv;
    float4 qp = cpts[n];
    float qx = qp.x, qy = qp.y, qz = qp.z, sqn = qp.w;
    unsigned keys[32];
    unsigned h[8];
#pragma unroll
    for (int k = 0; k < 8; k++) h[k] = 0xFFFFFFFFu;
#pragma unroll
    for (int j = 0; j < 32; j++) {
        float4 cp = cpts[j * 64 + lane];
        float dot = __fadd_rn(__fadd_rn(__fmul_rn(qx, cp.x), __fmul_rn(qy, cp.y)),
                              __fmul_rn(qz, cp.z));
        float d2 = __fsub_rn(__fadd_rn(sqn, cp.w), __fmul_rn(2.0f, dot));
        unsigned u = __float_as_uint(d2);
        u ^= (unsigned)(((int)u >> 31)) | 0x80000000u;  // order-preserving map
        keys[j] = u;
        unsigned cur = u;  // unconditional sorted-insert (no-op if u >= h[7])
#pragma unroll
        for (int t2 = 0; t2 < 8; t2++) {
            unsigned lo = h[t2] < cur ? h[t2] : cur;
            cur = h[t2] < cur ? cur : h[t2];
            h[t2] = lo;
        }
    }
    // Merge: serial-extract 8 smallest values of the union -> T8
    unsigned curh = h[0];
    unsigned T8 = 0;
#pragma unroll
    for (int r = 0; r < 8; r++) {
        unsigned w = curh;
#pragma unroll
        for (int off = 1; off < 64; off <<= 1) {
            unsigned o = __shfl_xor(w, off, 64);
            w = o < w ? o : w;
        }
        T8 = w;
        if (r < 7) {
            unsigned long long mask = __ballot(curh == w);
            if (curh == w && (mask & ((1ull << lane) - 1ull)) == 0) {
#pragma unroll
                for (int t2 = 0; t2 < 7; t2++) h[t2] = h[t2 + 1];
                h[7] = 0xFFFFFFFFu;
                curh = h[0];
            }
        }
    }
    // Pass 2: emit strict winners; track min eq index
    int* outr = idx + ((size_t)b * NPTS + n) * 8;
    int cnt = 0;
    unsigned meq = 0xFFFFFFFFu;
#pragma unroll
    for (int j = 0; j < 32; j++) {
        unsigned m = (unsigned)(j * 64 + lane);
        bool strict = keys[j] < T8;
        unsigned long long msk = __ballot(strict);
        if (strict) {
            int pos = cnt + (int)__popcll(msk & ((1ull << lane) - 1ull));
            outr[pos] = (int)m;
        }
        cnt += (int)__popcll(msk);
        if (keys[j] == T8 && m < meq) meq = m;
    }
    // Fill remaining slots with lowest-index key==T8 candidates
    while (cnt < 8) {
        unsigned w = meq;
#pragma unroll
        for (int off = 1; off < 64; off <<= 1) {
            unsigned o = __shfl_xor(w, off, 64);
            w = o < w ? o : w;
        }
        bool winner = (meq == w);
        if (winner) outr[cnt] = (int)w;
        cnt++;
        if (cnt >= 8) break;
        if (winner) {  // rare: advance to next eq index > w
            meq = 0xFFFFFFFFu;
#pragma unroll
            for (int j = 0; j < 32; j++) {
                unsigned m = (unsigned)(j * 64 + lane);
                if (keys[j] == T8 && m > w && m < meq) meq = m;
            }
        }
    }
}

// MFMA GEMM v10 = v9 ring-3/counted-vmcnt core + fused epilogues:
//  - vtout != nullptr (QKV gemm): blocks with col0 >= 768 also scatter their
//    bf16 outputs into VT [B,H,64,NPTS] (bit-identical to the old k_vt).
//  - outT != nullptr (final gemm): writes fp32 DIRECTLY to out [B,D,N]
//    (transposed), skipping the C store and one bf16 rounding.
__global__ __launch_bounds__(256) void k_gemm(const unsigned short* __restrict__ A, int lda,
                                              const unsigned short* __restrict__ WT,
                                              const float* __restrict__ bias,
                                              const unsigned short* __restrict__ res,
                                              unsigned short* __restrict__ C, int ldc,
                                              int K, int act, int NX,
                                              unsigned short* __restrict__ vtout,
                                              float* __restrict__ outT) {
    __shared__ unsigned short Alds[3][128 * 32];  // 3 x 8 KB ring: [slot][row][32]
    __shared__ unsigned short Wlds[3][128 * 32];  // 3 x 8 KB ring: [slot][nrow][32]
    int tid = threadIdx.x;
    int wv = tid >> 6, lane = tid & 63;
    int l15 = lane & 15, quad = lane >> 4;
    // XCD-aware block decode: id%8 = XCD (HW round-robin). 16 y-panels per XCD.
    int id = blockIdx.x;
    int xcd = id & 7, slot = id >> 3;
    int y = xcd * 16 + slot / NX;
    int x = slot % NX;
    int row0 = y * 128, col0 = x * 128;
    int wm = wv >> 1, wn = wv & 1;
    int wbase = tid & 192;  // wv*64
    floatx4 acc[4][4];
#pragma unroll
    for (int i = 0; i < 4; i++)
#pragma unroll
        for (int j = 0; j < 4; j++) acc[i][j] = (floatx4){0.f, 0.f, 0.f, 0.f};
    // stage one BK=32 chunk of A and W into ring slot sl (4 gloads per thread).
    auto stage = [&](int sl, int k0) {
#pragma unroll
        for (int i = 0; i < 2; i++) {
            int sid = i * 256 + tid;
            int row = sid >> 2, ko = sid & 3;
            gload_lds16(A + (size_t)(row0 + row) * lda + k0 + ko * 8,
                        &Alds[sl][(size_t)(i * 256 + wbase) * 8]);
            gload_lds16(WT + (size_t)(col0 + row) * K + k0 + ko * 8,
                        &Wlds[sl][(size_t)(i * 256 + wbase) * 8]);
        }
    };
    int nst = K >> 5;
    stage(0, 0);
    stage(1, 32);
    asm volatile("s_waitcnt vmcnt(4)" ::: "memory");  // slot 0 landed; slot 1 in flight
    __builtin_amdgcn_s_barrier();
    __builtin_amdgcn_sched_barrier(0);
    for (int t = 0; t < nst; ++t) {
        int sl = t % 3;
        if (t + 2 < nst) stage((t + 2) % 3, (t + 2) * 32);  // DMA 2 steps ahead
        short8 af[4], bf[4];
#pragma unroll
        for (int i = 0; i < 4; i++)
            af[i] = *(const short8*)&Alds[sl][(wm * 64 + i * 16 + l15) * 32 + quad * 8];
#pragma unroll
        for (int j = 0; j < 4; j++)
            bf[j] = *(const short8*)&Wlds[sl][(wn * 64 + j * 16 + l15) * 32 + quad * 8];
#pragma unroll
        for (int i = 0; i < 4; i++)
#pragma unroll
            for (int j = 0; j < 4; j++)
                acc[i][j] =
                    __builtin_amdgcn_mfma_f32_16x16x32_bf16(bf[j], af[i], acc[i][j], 0, 0, 0);
        if (t + 1 < nst) {
            if (t + 2 < nst)
                asm volatile("s_waitcnt vmcnt(4)" ::: "memory");  // (t+1) landed, (t+2) flying
            else
                asm volatile("s_waitcnt vmcnt(0)" ::: "memory");  // tail: drain last stage
            __builtin_amdgcn_s_barrier();
            __builtin_amdgcn_sched_barrier(0);
        }
    }
    // acc[i][j] is C^T-layout: D rows = n (quad*4+reg within j-tile), cols = m (l15)
#pragma unroll
    for (int i = 0; i < 4; i++) {
        int r = row0 + wm * 64 + i * 16 + l15;
#pragma unroll
        for (int j = 0; j < 4; j++) {
            int cb = col0 + wn * 64 + j * 16 + quad * 4;
            float4 bv = bias ? *(const float4*)(bias + cb) : make_float4(0.f, 0.f, 0.f, 0.f);
            float v0 = acc[i][j][0] + bv.x;
            float v1 = acc[i][j][1] + bv.y;
            float v2 = acc[i][j][2] + bv.z;
            float v3 = acc[i][j][3] + bv.w;
            if (act == 1) {
                v0 = gelu_tanh(v0); v1 = gelu_tanh(v1);
                v2 = gelu_tanh(v2); v3 = gelu_tanh(v3);
            }
            if (res) {
                uint2 rv = *(const uint2*)(res + (size_t)r * ldc + cb);
                const unsigned short* rs = (const unsigned short*)&rv;
                v0 += bf2f(rs[0]); v1 += bf2f(rs[1]);
                v2 += bf2f(rs[2]); v3 += bf2f(rs[3]);
            }
            if (outT) {  // fp32 transposed store to out [B, D, N]
                int bb = r >> 11, n = r & 2047;
                float* ob = outT + ((size_t)bb * D_MODEL + cb) * NPTS + n;
                ob[0] = v0; ob[NPTS] = v1; ob[2 * NPTS] = v2; ob[3 * NPTS] = v3;
            } else {
                ushort4 u;
                u.x = f2bf(v0); u.y = f2bf(v1); u.z = f2bf(v2); u.w = f2bf(v3);
                *(ushort4*)(C + (size_t)r * ldc + cb) = u;
                if (vtout && col0 >= 768) {  // V columns: also fill VT [B,H,64,NPTS]
                    int bb = r >> 11, n = r & 2047;
                    int dg = cb - 768;
                    unsigned short* vb =
                        vtout + ((size_t)(bb * NHEAD + (dg >> 6)) * 64 + (dg & 63)) * NPTS + n;
                    vb[0] = u.x; vb[NPTS] = u.y; vb[2 * NPTS] = u.z; vb[3 * NPTS] = u.w;
                }
            }
        }
    }
}

// MFMA flash attention v10 = v7 + P-only software pipeline (hazard-free):
// cross-iteration state is ONLY the P fragments (pure VALU register outputs,
// no memory hazard). V is read in the CONSUMING iteration from a 4-slot V
// ring (2 barriers of slack). K double-buffered. Body = QK(t)+softmax (serial
// chain) alongside PV(t-1) (independent loads+MFMAs). t=0 QK only; drain PV(31).
__global__ __launch_bounds__(256, 3) void k_attn(const unsigned short* __restrict__ qkv,
                                                 const unsigned short* __restrict__ vt,
                                                 unsigned short* __restrict__ attn) {
    __shared__ unsigned short Klds[2][64 * 64];  // 16 KB: [buf][key][dim] (swizzled slots)
    __shared__ unsigned short VTl[4][64 * 64];   // 32 KB: [slot][dim][key] (swizzled slots)
    // XCD decode: id%8 = XCD; 96 slots/XCD = 6 pairs x 16 tiles
    int id = blockIdx.x;
    int xcd = id & 7, slot = id >> 3;
    int pair = xcd * 6 + (slot >> 4);    // 48 pairs total, 6 per XCD
    int tile = slot & 15;
    int b = pair / 6, h = pair % 6;
    int tid = threadIdx.x;
    int wv = tid >> 6, lane = tid & 63;
    int l15 = lane & 15, quad = lane >> 4;
    int qbase = tile * 128 + wv * 32;
    const unsigned short* qkvb = qkv + (size_t)b * NPTS * 1152;
    const unsigned short* vtb = vt + (size_t)(b * NHEAD + h) * 64 * NPTS;
    const float SC = 0.18033688011112042f;  // 0.125 * log2(e)
    short8 qf[2][2];
#pragma unroll
    for (int qt = 0; qt < 2; qt++) {
        const unsigned short* qptr =
            qkvb + (size_t)(qbase + qt * 16 + l15) * 1152 + h * 64 + quad * 8;
        qf[qt][0] = *(const short8*)qptr;
        qf[qt][1] = *(const short8*)(qptr + 32);
#pragma unroll
        for (int g = 0; g < 2; g++) {  // fold softmax scale into Q once
            short8 v = qf[qt][g];
#pragma unroll
            for (int e = 0; e < 8; e++)
                v[e] = (short)f2bf(bf2f((unsigned short)v[e]) * SC);
            qf[qt][g] = v;
        }
    }
    short4v ones4;
#pragma unroll
    for (int e = 0; e < 4; e++) ones4[e] = (short)0x3F80;  // bf16 1.0
    int x7 = l15 & 7;
    int sk0 = ((quad ^ x7) << 4);        // K read: swizzled slot, dims 0..31
    int sk1 = (((quad + 4) ^ x7) << 4);  // K read: swizzled slot, dims 32..63
    int vslot[4];                        // V read: per-kt swizzled slot
#pragma unroll
    for (int kt = 0; kt < 4; kt++) vslot[kt] = (((kt * 2 + (quad >> 1)) ^ x7) << 4);
    int vsub = (quad & 1) * 8;           // 8B half within the 16B slot
    int sdg = tid & 7;                   // staging: 16B slot within row
    floatx4 o[2][4];
#pragma unroll
    for (int qt = 0; qt < 2; qt++)
#pragma unroll
        for (int ct = 0; ct < 4; ct++) o[qt][ct] = (floatx4){0.f, 0.f, 0.f, 0.f};
    floatx4 l4[2];
    l4[0] = (floatx4){0.f, 0.f, 0.f, 0.f};
    l4[1] = (floatx4){0.f, 0.f, 0.f, 0.f};

    // stage tile t: K -> Klds[t&1], V -> VTl[t&3]
    auto stage = [&](int t) {
        int k0 = t * 64;
#pragma unroll
        for (int i = 0; i < 2; i++) {
            int sid = i * 256 + tid;
            int row = sid >> 3;
            int sl = sdg ^ (row & 7);  // inverse-swizzled global slot
            gload_lds16(qkvb + (size_t)(k0 + row) * 1152 + 384 + h * 64 + sl * 8,
                        &Klds[t & 1][(size_t)(i * 256 + (tid & 192)) * 8]);
            gload_lds16(vtb + (size_t)row * NPTS + k0 + sl * 8,
                        &VTl[t & 3][(size_t)(i * 256 + (tid & 192)) * 8]);
        }
    };
    // QK^T(t) + softmax -> pfc (swapped operands: lane holds P[key][q=l15])
    auto qkchain = [&](int t, short4v (&pfc)[2][4]) {
        const char* Kb = (const char*)&Klds[t & 1][0];
        short8 kf[4][2];
#pragma unroll
        for (int ct = 0; ct < 4; ct++) {
            kf[ct][0] = *(const short8*)(Kb + (ct * 16 + l15) * 128 + sk0);
            kf[ct][1] = *(const short8*)(Kb + (ct * 16 + l15) * 128 + sk1);
        }
#pragma unroll
        for (int qt = 0; qt < 2; qt++) {
#pragma unroll
            for (int ct = 0; ct < 4; ct++) {
                floatx4 z = (floatx4){0.f, 0.f, 0.f, 0.f};
                z = __builtin_amdgcn_mfma_f32_16x16x32_bf16(kf[ct][0], qf[qt][0], z, 0, 0, 0);
                z = __builtin_amdgcn_mfma_f32_16x16x32_bf16(kf[ct][1], qf[qt][1], z, 0, 0, 0);
                float p0 = __builtin_amdgcn_exp2f(z[0]);
                float p1 = __builtin_amdgcn_exp2f(z[1]);
                float p2 = __builtin_amdgcn_exp2f(z[2]);
                float p3 = __builtin_amdgcn_exp2f(z[3]);
                u32x2 pk;
                pk.x = cvtpk(p0, p1);
                pk.y = cvtpk(p2, p3);
                pfc[qt][ct] = __builtin_bit_cast(short4v, pk);  // B-frag of mfma16
            }
        }
    };
    // PV(t): V read fresh from VTl[t&3] (consumed by MFMA in this iteration)
    auto pv = [&](int t, short4v (&pfp)[2][4]) {
        const char* Vb = (const char*)&VTl[t & 3][0] + l15 * 128 + vsub;
#pragma unroll
        for (int ctd = 0; ctd < 4; ctd++) {
            short4v va[4];
#pragma unroll
            for (int kt = 0; kt < 4; kt++)
                va[kt] = *(const short4v*)(Vb + ctd * 2048 + vslot[kt]);
#pragma unroll
            for (int kt = 0; kt < 4; kt++)
#pragma unroll
                for (int qt = 0; qt < 2; qt++)
                    o[qt][ctd] = mfma16(va[kt], pfp[qt][kt], o[qt][ctd]);
        }
#pragma unroll
        for (int qt = 0; qt < 2; qt++)
#pragma unroll
            for (int kt = 0; kt < 4; kt++) l4[qt] = mfma16(ones4, pfp[qt][kt], l4[qt]);
    };

    short4v pfA[2][4], pfB[2][4];
    stage(0);
    __syncthreads();
    stage(1);
    qkchain(0, pfA);  // no PV at t=0
    __syncthreads();
    for (int tt = 0; tt < 15; ++tt) {
        int t1 = 2 * tt + 1, t2 = 2 * tt + 2;
        stage(t1 + 1);           // tiles 2..30
        qkchain(t1, pfB);
        pv(t1 - 1, pfA);
        __syncthreads();
        stage(t2 + 1);           // tiles 3..31
        qkchain(t2, pfA);
        pv(t2 - 1, pfB);
        __syncthreads();
    }
    qkchain(31, pfB);
    pv(30, pfA);
    pv(31, pfB);  // V(31) staged at tt=14, drained by that body's barrier

#pragma unroll
    for (int qt = 0; qt < 2; qt++) {
        float linv = 1.0f / l4[qt][0];
#pragma unroll
        for (int ct = 0; ct < 4; ct++) {
            ushort4 u;
            u.x = f2bf(o[qt][ct][0] * linv);
            u.y = f2bf(o[qt][ct][1] * linv);
            u.z = f2bf(o[qt][ct][2] * linv);
            u.w = f2bf(o[qt][ct][3] * linv);
            *(ushort4*)(attn + ((size_t)b * NPTS + qbase + qt * 16 + l15) * 384 + h * 64 +
                        ct * 16 + quad * 4) = u;
        }
    }
}

// Graph attention: gq/nk/nv are column-slices of GAP [M,1152]. One wave per point.
// Writes geom into CAT[:, 384:768] (row stride 768).
__global__ __launch_bounds__(64) void k_geom(const unsigned short* __restrict__ gap,
                                             const int* __restrict__ idx,
                                             unsigned short* __restrict__ cat) {
    int r = blockIdx.x;
    int b = r >> 11;
    int t = threadIdx.x;
    int nb[8];
#pragma unroll
    for (int k = 0; k < 8; k++) nb[k] = idx[(size_t)r * 8 + k];
    const unsigned short* gqr = gap + (size_t)r * 1152;
    float qv[6];
#pragma unroll
    for (int j = 0; j < 6; j++) qv[j] = bf2f(gqr[t + 64 * j]);
    float s[8];
#pragma unroll
    for (int k = 0; k < 8; k++) {
        const unsigned short* nkr = gap + ((size_t)b * NPTS + nb[k]) * 1152 + 384;
        float acc = 0.0f;
#pragma unroll
        for (int j = 0; j < 6; j++) acc += qv[j] * bf2f(nkr[t + 64 * j]);
#pragma unroll
        for (int mm = 32; mm > 0; mm >>= 1) acc += __shfl_xor(acc, mm, 64);
        s[k] = acc * 0.05103103630798287f;  // 1/sqrt(384)
    }
    float mx = s[0];
#pragma unroll
    for (int k = 1; k < 8; k++) mx = fmaxf(mx, s[k]);
    float w[8];
    float sum = 0.0f;
#pragma unroll
    for (int k = 0; k < 8; k++) { w[k] = __expf(s[k] - mx); sum += w[k]; }
    float inv = 1.0f / sum;
    unsigned short* outr = cat + (size_t)r * 768 + 384;
#pragma unroll
    for (int j = 0; j < 6; j++) {
        int d = t + 64 * j;
        float acc = 0.0f;
#pragma unroll
        for (int k = 0; k < 8; k++)
            acc += w[k] * bf2f(gap[((size_t)b * NPTS + nb[k]) * 1152 + 768 + d]);
        outr[d] = f2bf(acc * inv);
    }
}

extern "C" void kernel_launch(void* const* d_in, const int* in_sizes, int n_in,
                              void* d_out, int out_size, void* d_ws, size_t ws_size,
                              hipStream_t stream) {
    (void)in_sizes; (void)n_in; (void)out_size; (void)ws_size;
    const float* coords     = (const float*)d_in[0];
    const float* features   = (const float*)d_in[1];
    const float* ln1_g      = (const float*)d_in[2];
    const float* ln1_b      = (const float*)d_in[3];
    const float* w_qkv      = (const float*)d_in[4];
    const float* w_attn_out = (const float*)d_in[5];
    const float* b_attn_out = (const float*)d_in[6];
    const float* ga_wq      = (const float*)d_in[7];
    const float* ga_wk      = (const float*)d_in[8];
    const float* ga_wv      = (const float*)d_in[9];
    const float* merge_w    = (const float*)d_in[10];
    const float* merge_b    = (const float*)d_in[11];
    const float* ln2_g      = (const float*)d_in[12];
    const float* ln2_b      = (const float*)d_in[13];
    const float* ff_w1      = (const float*)d_in[14];
    const float* ff_b1      = (const float*)d_in[15];
    const float* ff_w2      = (const float*)d_in[16];
    const float* ff_b2      = (const float*)d_in[17];

    // Workspace (bf16 units of SZ = 6,291,456 elems = 12 MiB). Overlay schedule:
    //   u0 F | u1 NF->HB | u2-4 QKV -> (CAT=u2-3, GAP=u4-6 after attn/AO) |
    //   u5 ATTN | u6 VT (dead before GAP gemm) | F2=u4 after geom | T1=u5-6 |
    //   IDX + transposed weights after u7 (~4.3 MB).
    unsigned short* W0 = (unsigned short*)d_ws;
    const size_t SZ = (size_t)BATCH * NPTS * D_MODEL;  // 6291456
    unsigned short* F    = W0 + 0 * SZ;
    unsigned short* NF   = W0 + 1 * SZ;
    unsigned short* QKV  = W0 + 2 * SZ;   // 3 units
    unsigned short* ATTN = W0 + 5 * SZ;
    unsigned short* VT   = W0 + 6 * SZ;   // [B,H,64,NPTS] = 1 unit
    unsigned short* CAT  = W0 + 2 * SZ;   // 2 units [M,768]
    unsigned short* GAP  = W0 + 4 * SZ;   // 3 units [M,1152]
    unsigned short* F2   = W0 + 4 * SZ;   // after GAP dead
    unsigned short* HB   = W0 + 1 * SZ;
    unsigned short* T1   = W0 + 5 * SZ;   // 2 units [M,768]
    int*            IDX  = (int*)(W0 + 7 * SZ);
    unsigned short* WTS  = W0 + 7 * SZ + 262144;  // after IDX (512 KB)
    unsigned short* qkvT = WTS;                     // [1152,384]
    unsigned short* aoT  = qkvT + 442368;           // [384,384]
    unsigned short* gaT  = aoT + 147456;            // [1152,384]
    unsigned short* mT   = gaT + 442368;            // [384,768]
    unsigned short* f1T  = mT + 294912;             // [768,384]
    unsigned short* f2T  = f1T + 294912;            // [384,768]

    const int M = BATCH * NPTS;  // 16384

    k_wprep<<<1872, dim3(32, 8), 0, stream>>>(w_qkv, w_attn_out, ga_wq, ga_wk, ga_wv,
                                              merge_w, ff_w1, ff_w2,
                                              qkvT, aoT, gaT, mT, f1T, f2T);
    // fused transpose_in + LN1
    k_lnin<<<dim3(NPTS / 32, BATCH), 256, 0, stream>>>(features, ln1_g, ln1_b, F, NF);
    k_knn<<<BATCH * (NPTS / 4), 256, 0, stream>>>(coords, IDX);
    // QKV = NF @ w_qkv  (+ fused V-transpose into VT)
    k_gemm<<<9 * 128, 256, 0, stream>>>(NF, 384, qkvT, nullptr, nullptr,
                                        QKV, 1152, 384, 0, 9, VT, nullptr);
    k_attn<<<768, 256, 0, stream>>>(QKV, VT, ATTN);
    // CAT[:, :384] = ATTN @ w_attn_out + b_attn_out
    k_gemm<<<3 * 128, 256, 0, stream>>>(ATTN, 384, aoT, b_attn_out, nullptr,
                                        CAT, 768, 384, 0, 3, nullptr, nullptr);
    // GAP = NF @ [ga_wq | ga_wk | ga_wv]
    k_gemm<<<9 * 128, 256, 0, stream>>>(NF, 384, gaT, nullptr, nullptr,
                                        GAP, 1152, 384, 0, 9, nullptr, nullptr);
    k_geom<<<M, 64, 0, stream>>>(GAP, IDX, CAT);
    // F2 = CAT @ merge_w + merge_b + F
    k_gemm<<<3 * 128, 256, 0, stream>>>(CAT, 768, mT, merge_b, F,
                                        F2, 384, 768, 0, 3, nullptr, nullptr);
    k_layernorm<<<M, 128, 0, stream>>>(F2, ln2_g, ln2_b, HB);
    // T1 = gelu(HB @ ff_w1 + ff_b1)
    k_gemm<<<6 * 128, 256, 0, stream>>>(HB, 384, f1T, ff_b1, nullptr,
                                        T1, 768, 384, 1, 6, nullptr, nullptr);
    // out[B,D,N] = transpose(F2 + T1 @ ff_w2 + ff_b2)  (fused fp32 store)
    k_gemm<<<3 * 128, 256, 0, stream>>>(T1, 768, f2T, ff_b2, F2,
                                        nullptr, 384, 768, 0, 3, nullptr, (float*)d_out);
}